// Round 1
// baseline (1128.739 us; speedup 1.0000x reference)
//
#include <hip/hip_runtime.h>

#define TT 2048
#define BB 128
#define II 32
#define HH 128

// One block per batch element. 512 threads = 8 waves.
// Thread (h = tid>>2, k = tid&3): owns hidden unit h, K-chunk k (32 of 128).
// W_hh row chunk lives in registers. h state double-buffered in LDS
// (chunk-padded 36-float groups -> conflict-free broadcast b128 reads).
// xproj fused (W_in in registers). X rows staged 2 windows (16 steps) ahead
// into LDS by wave 0 to hide HBM latency. Raw s_barrier (lgkmcnt-only drain)
// keeps staged global loads in flight across barriers.
__global__ __launch_bounds__(512)
void vrnn_kernel(const float* __restrict__ X, const float* __restrict__ W_in,
                 const float* __restrict__ W_hh, const float* __restrict__ rnn_bias,
                 const float* __restrict__ alpha, const float* __restrict__ value_W,
                 const float* __restrict__ value_bias, float* __restrict__ out)
{
    const int b    = blockIdx.x;
    const int tid  = threadIdx.x;
    const int h    = tid >> 2;   // 0..127
    const int k    = tid & 3;    // 0..3
    const int wave = tid >> 6;   // 0..7
    const int lane = tid & 63;

    __shared__ __align__(16) float hbuf[2 * 144];   // h state, double-buffered, 36-padded
    __shared__ __align__(16) float xs[2 * 288];     // X window: 8 rows x 36 floats, dbuf
    __shared__ float vpart[2][8];                   // per-wave V partials, dbuf

    // ---- preload weights into registers ----
    float4 wv[8];
    const float4* wrow = reinterpret_cast<const float4*>(W_hh + h * HH + 32 * k);
#pragma unroll
    for (int i = 0; i < 8; ++i) wv[i] = wrow[i];
    const float4* wirow = reinterpret_cast<const float4*>(W_in + h * II + 8 * k);
    const float4 wi0 = wirow[0];
    const float4 wi1 = wirow[1];
    const float bias = rnn_bias[h];
    const float al   = alpha[h];
    const float vw   = value_W[h];      // O == 1
    const float vb   = value_bias[0];

    // ---- init h state (buffer 0) ----
    if (tid < 144) hbuf[tid] = 0.0f;

    // ---- X staging prologue: window 0 -> xs buf0; issue window 1 loads ----
    const int xr = lane >> 3;          // row within window 0..7
    const int xc = (lane & 7) * 4;     // float col 0,4,...,28
    float4 xpend;                      // in-flight window (wave 0 only)
    if (wave == 0) {
        float4 w0 = *reinterpret_cast<const float4*>(X + (size_t)xr * (BB * II) + b * II + xc);
        int row1 = 8 + xr;
        xpend = *reinterpret_cast<const float4*>(X + (size_t)row1 * (BB * II) + b * II + xc);
        *reinterpret_cast<float4*>(&xs[xr * 36 + xc]) = w0;
    }
    float hval = 0.0f;
    __syncthreads();

    float* outV = out;                         // (T,B,1) flat
    float* outH = out + (size_t)TT * BB;       // last_hidden (B,H)

    for (int t = 0; t < TT; ++t) {
        // [A] window boundary: publish pending window, issue next (wave 0)
        if ((t & 7) == 0 && wave == 0) {
            const int i = t >> 3;
            *reinterpret_cast<float4*>(&xs[((i + 1) & 1) * 288 + xr * 36 + xc]) = xpend;
            int row = (i + 2) * 8 + xr;
            if (row > TT - 1) row = TT - 1;
            xpend = *reinterpret_cast<const float4*>(X + (size_t)row * (BB * II) + b * II + xc);
        }
        // [B] combine previous step's V partials (off critical path)
        if (t > 0 && tid == 0) {
            const float* vp = vpart[(t - 1) & 1];
            float s = vb;
#pragma unroll
            for (int w = 0; w < 8; ++w) s += vp[w];
            outV[(size_t)(t - 1) * BB + b] = s;
        }
        // [C] read h_prev chunk (broadcast, conflict-free) + x row chunk
        const float* hb = &hbuf[(t & 1) * 144 + 36 * k];
        float4 hp[8];
#pragma unroll
        for (int i = 0; i < 8; ++i) hp[i] = reinterpret_cast<const float4*>(hb)[i];
        const float* xrow = &xs[((t >> 3) & 1) * 288 + (t & 7) * 36 + 8 * k];
        const float4 x0 = reinterpret_cast<const float4*>(xrow)[0];
        const float4 x1 = reinterpret_cast<const float4*>(xrow)[1];
        // [D] partial dots (4 independent FMA chains + 2 for xproj)
        float a0 = 0.f, a1 = 0.f, a2 = 0.f, a3 = 0.f;
#pragma unroll
        for (int i = 0; i < 8; ++i) {
            a0 = fmaf(wv[i].x, hp[i].x, a0);
            a1 = fmaf(wv[i].y, hp[i].y, a1);
            a2 = fmaf(wv[i].z, hp[i].z, a2);
            a3 = fmaf(wv[i].w, hp[i].w, a3);
        }
        float xa = 0.f, xb = 0.f;
        xa = fmaf(wi0.x, x0.x, xa); xa = fmaf(wi0.y, x0.y, xa);
        xa = fmaf(wi0.z, x0.z, xa); xa = fmaf(wi0.w, x0.w, xa);
        xb = fmaf(wi1.x, x1.x, xb); xb = fmaf(wi1.y, x1.y, xb);
        xb = fmaf(wi1.z, x1.z, xb); xb = fmaf(wi1.w, x1.w, xb);
        float pre = ((a0 + a1) + (a2 + a3)) + (xa + xb);
        // reduce over the 4 K-chunks (butterfly: all 4 lanes get the sum)
        pre += __shfl_xor(pre, 1);
        pre += __shfl_xor(pre, 2);
        const float xv = pre + bias;
        // tanh(xv) = 1 - 2/(exp(2*xv)+1), via v_exp_f32 / v_rcp_f32
        const float e  = __builtin_amdgcn_exp2f(xv * 2.8853900817779268f);
        const float r  = __builtin_amdgcn_rcpf(e + 1.0f);
        const float ht = fmaf(-2.0f, r, 1.0f);
        hval = fmaf(al, ht - hval, hval);    // (1-a)*h + a*ht
        // [E] publish h_new; V partial (one lane per h in the xor-orbit)
        if (k == 0) hbuf[((t + 1) & 1) * 144 + 36 * (h >> 5) + (h & 31)] = hval;
        float c = vw * hval;
        c += __shfl_xor(c, 4);
        c += __shfl_xor(c, 8);
        c += __shfl_xor(c, 16);
        c += __shfl_xor(c, 32);
        if (lane == 0) vpart[t & 1][wave] = c;
        // [F] barrier: publish LDS writes WITHOUT draining vmcnt (keeps X
        // prefetch loads in flight across the barrier)
        asm volatile("s_waitcnt lgkmcnt(0)" ::: "memory");
        __builtin_amdgcn_s_barrier();
    }
    // epilogue: V for t = T-1, last_hidden
    if (tid == 0) {
        const float* vp = vpart[(TT - 1) & 1];
        float s = vb;
#pragma unroll
        for (int w = 0; w < 8; ++w) s += vp[w];
        outV[(size_t)(TT - 1) * BB + b] = s;
    }
    if (k == 0) outH[b * HH + h] = hval;
}

extern "C" void kernel_launch(void* const* d_in, const int* in_sizes, int n_in,
                              void* d_out, int out_size, void* d_ws, size_t ws_size,
                              hipStream_t stream) {
    const float* X      = (const float*)d_in[0];
    const float* W_in   = (const float*)d_in[1];
    const float* W_hh   = (const float*)d_in[2];
    const float* rbias  = (const float*)d_in[3];
    const float* alpha  = (const float*)d_in[4];
    const float* vW     = (const float*)d_in[5];
    const float* vbias  = (const float*)d_in[6];
    float* out = (float*)d_out;

    vrnn_kernel<<<dim3(BB), dim3(512), 0, stream>>>(X, W_in, W_hh, rbias, alpha, vW, vbias, out);
}

// Round 2
// 755.620 us; speedup vs baseline: 1.4938x; 1.4938x over previous
//
#include <hip/hip_runtime.h>

#define TT 2048
#define BB 128
#define II 32
#define HH 128

typedef float v2f __attribute__((ext_vector_type(2)));
typedef float v4f __attribute__((ext_vector_type(4)));

// packed dual fp32 FMA (VOP3P) — halves FMA issue count
__device__ __forceinline__ v2f pk_fma(v2f a, v2f b, v2f c) {
    v2f d;
    asm("v_pk_fma_f32 %0, %1, %2, %3" : "=v"(d) : "v"(a), "v"(b), "v"(c));
    return d;
}

// fused add of DPP-permuted self: p + dpp(p). CTRL: 0xB1=quad xor1,
// 0x4E=quad xor2, 0x124=row_ror:4, 0x128=row_ror:8 (16-lane domain).
template <int CTRL>
__device__ __forceinline__ float dpp_add(float p) {
    int t = __builtin_amdgcn_update_dpp(0, __float_as_int(p), CTRL, 0xF, 0xF, true);
    return p + __int_as_float(t);
}

// One block per batch element, 512 threads = 8 waves.
// Wave w, group g = lane>>4 (one 16-lane DPP row), j = lane&15.
// (w,g) owns rows base..base+3 (base = 16w+4g); lane j covers cols 8j..8j+7.
// All reductions via DPP/readlane (no LDS shuffles). h state double-buffered
// in LDS (plain [2][128]); X staged 2 windows ahead by wave 0; raw s_barrier
// with lgkmcnt-only drain keeps prefetch loads in flight.
__global__ __launch_bounds__(512)
void vrnn_kernel(const float* __restrict__ X, const float* __restrict__ W_in,
                 const float* __restrict__ W_hh, const float* __restrict__ rnn_bias,
                 const float* __restrict__ alpha, const float* __restrict__ value_W,
                 const float* __restrict__ value_bias, float* __restrict__ out)
{
    const int b    = blockIdx.x;
    const int tid  = threadIdx.x;
    const int wave = tid >> 6;
    const int lane = tid & 63;
    const int g    = lane >> 4;
    const int j    = lane & 15;
    const int base = 16 * wave + 4 * g;      // first of this group's 4 rows

    __shared__ __align__(16) float hbuf[2 * HH];
    __shared__ __align__(16) float xs[2 * 288];      // 8 rows x 36 floats, dbuf
    __shared__ __align__(16) float vpart[2][8];

    // ---- per-thread constants ----
    v2f wh[4][4], wi[4], binit[4];
#pragma unroll
    for (int r = 0; r < 4; ++r) {
        const float* wr = W_hh + (size_t)(base + r) * HH + 8 * j;
        v4f a0 = *reinterpret_cast<const v4f*>(wr);
        v4f a1 = *reinterpret_cast<const v4f*>(wr + 4);
        wh[r][0] = (v2f){a0.x, a0.y}; wh[r][1] = (v2f){a0.z, a0.w};
        wh[r][2] = (v2f){a1.x, a1.y}; wh[r][3] = (v2f){a1.z, a1.w};
        wi[r] = *reinterpret_cast<const v2f*>(W_in + (size_t)(base + r) * II + 2 * j);
        binit[r] = (v2f){ (j == 0) ? rnn_bias[base + r] : 0.0f, 0.0f };
    }
    const bool j1 = (j & 1) != 0;
    const bool j2 = (j & 2) != 0;
    const float al     = alpha[base + (j & 3)];
    const float vw_eff = (j < 4) ? value_W[base + j] : 0.0f;
    const float vb     = value_bias[0];

    // ---- init h state buffer 0 ----
    if (tid < HH) hbuf[tid] = 0.0f;

    // ---- X staging prologue (wave 0): window 0 stored, window 1 in flight ----
    const int xr = lane >> 3;
    const int xc = (lane & 7) * 4;
    v4f xpend;
    if (wave == 0) {
        v4f w0 = *reinterpret_cast<const v4f*>(X + (size_t)xr * (BB * II) + b * II + xc);
        xpend  = *reinterpret_cast<const v4f*>(X + (size_t)(8 + xr) * (BB * II) + b * II + xc);
        *reinterpret_cast<v4f*>(&xs[xr * 36 + xc]) = w0;
    }
    float hval = 0.0f;
    __syncthreads();

    float* outV = out;
    float* outH = out + (size_t)TT * BB;

    for (int t2 = 0; t2 < TT / 16; ++t2) {
#pragma unroll
        for (int s = 0; s < 16; ++s) {
            // ---- [A] window staging (slots 0 and 8; wave 0 only) ----
            if ((s & 7) == 0 && wave == 0) {
                *reinterpret_cast<v4f*>(&xs[(((s >> 3) + 1) & 1) * 288 + xr * 36 + xc]) = xpend;
                int row = (t2 << 4) + ((s >> 3) << 3) + 16 + xr;
                if (row > TT - 1) row = TT - 1;
                xpend = *reinterpret_cast<const v4f*>(X + (size_t)row * (BB * II) + b * II + xc);
            }
            // ---- [B] combine previous step's V partials (tid 0) ----
            if ((s != 0 || t2 != 0) && tid == 0) {
                const float* vp = vpart[(s & 1) ^ 1];
                float sum = vb;
#pragma unroll
                for (int w = 0; w < 8; ++w) sum += vp[w];
                const int t = (t2 << 4) + s;
                outV[(size_t)(t - 1) * BB + b] = sum;
            }
            // ---- [C] read h chunk (8 floats) + x pair ----
            const float* hb = &hbuf[(s & 1) * HH + 8 * j];
            v4f h0 = *reinterpret_cast<const v4f*>(hb);
            v4f h1 = *reinterpret_cast<const v4f*>(hb + 4);
            v2f hc0 = (v2f){h0.x, h0.y}, hc1 = (v2f){h0.z, h0.w};
            v2f hc2 = (v2f){h1.x, h1.y}, hc3 = (v2f){h1.z, h1.w};
            v2f xv = *reinterpret_cast<const v2f*>(&xs[((s >> 3) & 1) * 288 + (s & 7) * 36 + 2 * j]);
            // ---- [D] 4 rows x 8 cols packed FMAs + DPP 16-lane reduce ----
            float p0, p1, p2, p3;
            {
                v2f a;
                a = binit[0];
                a = pk_fma(wh[0][0], hc0, a); a = pk_fma(wh[0][1], hc1, a);
                a = pk_fma(wh[0][2], hc2, a); a = pk_fma(wh[0][3], hc3, a);
                a = pk_fma(wi[0], xv, a);
                p0 = a.x + a.y;
                a = binit[1];
                a = pk_fma(wh[1][0], hc0, a); a = pk_fma(wh[1][1], hc1, a);
                a = pk_fma(wh[1][2], hc2, a); a = pk_fma(wh[1][3], hc3, a);
                a = pk_fma(wi[1], xv, a);
                p1 = a.x + a.y;
                a = binit[2];
                a = pk_fma(wh[2][0], hc0, a); a = pk_fma(wh[2][1], hc1, a);
                a = pk_fma(wh[2][2], hc2, a); a = pk_fma(wh[2][3], hc3, a);
                a = pk_fma(wi[2], xv, a);
                p2 = a.x + a.y;
                a = binit[3];
                a = pk_fma(wh[3][0], hc0, a); a = pk_fma(wh[3][1], hc1, a);
                a = pk_fma(wh[3][2], hc2, a); a = pk_fma(wh[3][3], hc3, a);
                a = pk_fma(wi[3], xv, a);
                p3 = a.x + a.y;
            }
            p0 = dpp_add<0xB1>(p0); p0 = dpp_add<0x4E>(p0); p0 = dpp_add<0x124>(p0); p0 = dpp_add<0x128>(p0);
            p1 = dpp_add<0xB1>(p1); p1 = dpp_add<0x4E>(p1); p1 = dpp_add<0x124>(p1); p1 = dpp_add<0x128>(p1);
            p2 = dpp_add<0xB1>(p2); p2 = dpp_add<0x4E>(p2); p2 = dpp_add<0x124>(p2); p2 = dpp_add<0x128>(p2);
            p3 = dpp_add<0xB1>(p3); p3 = dpp_add<0x4E>(p3); p3 = dpp_add<0x124>(p3); p3 = dpp_add<0x128>(p3);
            // ---- [E] select own row, tanh, blend ----
            const float sa  = j1 ? p1 : p0;
            const float sb  = j1 ? p3 : p2;
            const float pre = j2 ? sb : sa;
            const float e  = __builtin_amdgcn_exp2f(pre * 2.8853900817779268f);
            const float rc = __builtin_amdgcn_rcpf(e + 1.0f);
            const float ht = fmaf(-2.0f, rc, 1.0f);
            hval = fmaf(al, ht - hval, hval);
            // ---- [F] publish h_new (lanes j<4), V partial via DPP+readlane ----
            if (j < 4) hbuf[((s & 1) ^ 1) * HH + base + j] = hval;
            float c = vw_eff * hval;
            c = dpp_add<0xB1>(c); c = dpp_add<0x4E>(c);   // quad 0 of each row = group sum
            const float c1 = __int_as_float(__builtin_amdgcn_readlane(__float_as_int(c), 16));
            const float c2 = __int_as_float(__builtin_amdgcn_readlane(__float_as_int(c), 32));
            const float c3 = __int_as_float(__builtin_amdgcn_readlane(__float_as_int(c), 48));
            if (lane == 0) vpart[s & 1][wave] = c + c1 + c2 + c3;
            // ---- [G] barrier: drain LDS only, keep global loads in flight ----
            asm volatile("s_waitcnt lgkmcnt(0)" ::: "memory");
            __builtin_amdgcn_s_barrier();
            __builtin_amdgcn_sched_barrier(0);
        }
    }
    // ---- epilogue: V[T-1], last_hidden ----
    if (tid == 0) {
        const float* vp = vpart[(TT - 1) & 1];
        float sum = vb;
#pragma unroll
        for (int w = 0; w < 8; ++w) sum += vp[w];
        outV[(size_t)(TT - 1) * BB + b] = sum;
    }
    if (j < 4) outH[b * HH + base + j] = hval;
}

extern "C" void kernel_launch(void* const* d_in, const int* in_sizes, int n_in,
                              void* d_out, int out_size, void* d_ws, size_t ws_size,
                              hipStream_t stream) {
    const float* X      = (const float*)d_in[0];
    const float* W_in   = (const float*)d_in[1];
    const float* W_hh   = (const float*)d_in[2];
    const float* rbias  = (const float*)d_in[3];
    const float* alpha  = (const float*)d_in[4];
    const float* vW     = (const float*)d_in[5];
    const float* vbias  = (const float*)d_in[6];
    float* out = (float*)d_out;

    vrnn_kernel<<<dim3(BB), dim3(512), 0, stream>>>(X, W_in, W_hh, rbias, alpha, vW, vbias, out);
}